// Round 7
// baseline (68.278 us; speedup 1.0000x reference)
//
#include <hip/hip_runtime.h>

// Problem: B=4, N=512, D=256, H=256, M = B*N = 2048
// out[b,i,j] = 0.5*(E + E^T),  E[b,i,j] = sum_h v[h]*tanh(Q[b,i,h]+K[b,j,h])
// tanh(q+k) = 1 - 2/(1+e^{2q}e^{2k}); u=exp2(C2*q), w=exp2(C2*k), C2=2*log2(e)
// P_ij = sum_h v_h/(1+u_ih w_jh);  out_ij = Sv - (P_ij + P_ji)
// 2-way rcp batching: v0/A0 + v1/A1 = (v0*A1 + v1*A0)/(A0*A1), A_t = 1+u_t w_t.
// GEMM fold: Q = h1 @ (Wq@W2)^T + (Wq@b2+bq)

typedef float f2 __attribute__((ext_vector_type(2)));
typedef float f4 __attribute__((ext_vector_type(4)));
typedef float f32x4 __attribute__((ext_vector_type(4)));
typedef __bf16 bf16x8 __attribute__((ext_vector_type(8)));

#define C2F 2.8853900817779268f

__device__ inline unsigned short f2bf(float f) {
    unsigned u = __float_as_uint(f);
    unsigned r = (u + 0x7fffu + ((u >> 16) & 1u)) >> 16;
    return (unsigned short)r;
}
__device__ inline float bf2f(unsigned short h) {
    return __uint_as_float(((unsigned)h) << 16);
}

__device__ inline void split4(const f4 a, unsigned short* hp, unsigned short* lp) {
    unsigned short h[4], l[4];
#pragma unroll
    for (int t = 0; t < 4; ++t) {
        h[t] = f2bf(a[t]);
        l[t] = f2bf(a[t] - bf2f(h[t]));
    }
    uint2 hv, lv;
    hv.x = (unsigned)h[0] | ((unsigned)h[1] << 16);
    hv.y = (unsigned)h[2] | ((unsigned)h[3] << 16);
    lv.x = (unsigned)l[0] | ((unsigned)l[1] << 16);
    lv.y = (unsigned)l[2] | ((unsigned)l[3] << 16);
    *(uint2*)hp = hv;
    *(uint2*)lp = lv;
}

// ---------------------------------------------------------------------------
// gemm_fullk: C[m,n] = act( sum_k A[m,k]*Wsel[n,k] + bias[n] ), K=256 resident.
// ACT: 1=tanh, 2=exp2(C2*x) clamped to [0,1e4]
// ---------------------------------------------------------------------------
template <int ACT>
__global__ __launch_bounds__(256) void gemm_fullk(
    const float* __restrict__ A, const float* __restrict__ Wa,
    const float* __restrict__ Wb, const float* __restrict__ ba,
    const float* __restrict__ bb2, float* __restrict__ C, int Nn) {
    __shared__ unsigned short sAhi[64][264];
    __shared__ unsigned short sAlo[64][264];
    __shared__ unsigned short sBhi[64][264];
    __shared__ unsigned short sBlo[64][264];

    const int tid = threadIdx.x;
    const int m0 = blockIdx.x << 6;
    const int n0 = blockIdx.y << 6;

    const float* Atile = A + (size_t)m0 * 256;
    const float* Wtile = (n0 < 256) ? (Wa + (size_t)n0 * 256)
                                    : (Wb + (size_t)(n0 - 256) * 256);
    const int col4 = (tid & 63) << 2;
    const int rgrp = tid >> 6;
#pragma unroll
    for (int t = 0; t < 16; ++t) {
        const int row = (t << 2) + rgrp;
        f4 av = *(const f4*)&Atile[(size_t)row * 256 + col4];
        f4 wv = *(const f4*)&Wtile[(size_t)row * 256 + col4];
        split4(av, &sAhi[row][col4], &sAlo[row][col4]);
        split4(wv, &sBhi[row][col4], &sBlo[row][col4]);
    }
    __syncthreads();

    const int lane = tid & 63;
    const int wav = tid >> 6;
    const int wm = wav >> 1, wn = wav & 1;
    const int fr = lane & 15;
    const int fks = (lane >> 4) << 3;

    f32x4 acc[2][2];
#pragma unroll
    for (int i = 0; i < 2; ++i)
#pragma unroll
        for (int j = 0; j < 2; ++j) acc[i][j] = (f32x4){0.f, 0.f, 0.f, 0.f};

#pragma unroll
    for (int kt = 0; kt < 256; kt += 32) {
        bf16x8 ah[2], al[2], bh[2], bl[2];
#pragma unroll
        for (int s = 0; s < 2; ++s) {
            ah[s] = *(const bf16x8*)&sAhi[(wm << 5) + (s << 4) + fr][kt + fks];
            al[s] = *(const bf16x8*)&sAlo[(wm << 5) + (s << 4) + fr][kt + fks];
            bh[s] = *(const bf16x8*)&sBhi[(wn << 5) + (s << 4) + fr][kt + fks];
            bl[s] = *(const bf16x8*)&sBlo[(wn << 5) + (s << 4) + fr][kt + fks];
        }
#pragma unroll
        for (int i = 0; i < 2; ++i)
#pragma unroll
            for (int j = 0; j < 2; ++j) {
                acc[i][j] = __builtin_amdgcn_mfma_f32_16x16x32_bf16(ah[i], bh[j], acc[i][j], 0, 0, 0);
                acc[i][j] = __builtin_amdgcn_mfma_f32_16x16x32_bf16(ah[i], bl[j], acc[i][j], 0, 0, 0);
                acc[i][j] = __builtin_amdgcn_mfma_f32_16x16x32_bf16(al[i], bh[j], acc[i][j], 0, 0, 0);
            }
    }

    const int rbase = (lane >> 4) << 2;
#pragma unroll
    for (int i = 0; i < 2; ++i) {
#pragma unroll
        for (int j = 0; j < 2; ++j) {
            const int gcol = n0 + (wn << 5) + (j << 4) + fr;
            const float bias = (ACT == 2 && gcol >= 256) ? bb2[gcol - 256] : ba[gcol];
#pragma unroll
            for (int q = 0; q < 4; ++q) {
                const int grow = m0 + (wm << 5) + (i << 4) + rbase + q;
                float x = acc[i][j][q] + bias;
                if (ACT == 1)
                    x = 1.0f - 2.0f * __builtin_amdgcn_rcpf(
                                          1.0f + __builtin_amdgcn_exp2f(C2F * x));
                if (ACT == 2)
                    x = fminf(__builtin_amdgcn_exp2f(C2F * x), 1.0e4f);
                C[(size_t)grow * Nn + gcol] = x;
            }
        }
    }
}

// ---------------------------------------------------------------------------
// gemm_stage1: fused launch.
//  blocks [0,128): h1 = tanh(X @ W1^T + b1)
//  blocks [128,160): Wc = [Wq;Wk] @ W2 (B not transp.), bc = Asel@b2 + bias
// ---------------------------------------------------------------------------
__global__ __launch_bounds__(256) void gemm_stage1(
    const float* __restrict__ X, const float* __restrict__ W1,
    const float* __restrict__ b1, const float* __restrict__ Wq,
    const float* __restrict__ Wk, const float* __restrict__ W2,
    const float* __restrict__ b2, const float* __restrict__ bq,
    const float* __restrict__ bk, float* __restrict__ h1,
    float* __restrict__ Wc, float* __restrict__ bc) {
    __shared__ unsigned short sAhi[64][264];
    __shared__ unsigned short sAlo[64][264];
    __shared__ unsigned short sBhi[64][264];
    __shared__ unsigned short sBlo[64][264];
    __shared__ float sred[64][4];

    const int tid = threadIdx.x;
    const bool is_nt = (blockIdx.x >= 128);
    const int blk = is_nt ? (blockIdx.x - 128) : blockIdx.x;
    const int m0 = (blk >> 2) << 6;
    const int n0 = (blk & 3) << 6;

    const int col4 = (tid & 63) << 2;
    const int rgrp = tid >> 6;

    if (!is_nt) {
        const float* Atile = X + (size_t)m0 * 256;
        const float* Wtile = W1 + (size_t)n0 * 256;
#pragma unroll
        for (int t = 0; t < 16; ++t) {
            const int row = (t << 2) + rgrp;
            f4 av = *(const f4*)&Atile[(size_t)row * 256 + col4];
            f4 wv = *(const f4*)&Wtile[(size_t)row * 256 + col4];
            split4(av, &sAhi[row][col4], &sAlo[row][col4]);
            split4(wv, &sBhi[row][col4], &sBlo[row][col4]);
        }
    } else {
        const float* Atile = (m0 < 256) ? (Wq + (size_t)m0 * 256)
                                        : (Wk + (size_t)(m0 - 256) * 256);
#pragma unroll
        for (int t = 0; t < 16; ++t) {
            const int row = (t << 2) + rgrp;
            f4 av = *(const f4*)&Atile[(size_t)row * 256 + col4];
            split4(av, &sAhi[row][col4], &sAlo[row][col4]);
        }
        const int c4 = (tid & 15) << 2;
        const int kg = tid >> 4;
#pragma unroll
        for (int t = 0; t < 16; ++t) {
            const int k = (t << 4) + kg;
            f4 wv = *(const f4*)&W2[(size_t)k * 256 + n0 + c4];
#pragma unroll
            for (int q = 0; q < 4; ++q) {
                unsigned short hi = f2bf(wv[q]);
                sBhi[c4 + q][k] = hi;
                sBlo[c4 + q][k] = f2bf(wv[q] - bf2f(hi));
            }
        }
    }
    __syncthreads();

    const int lane = tid & 63;
    const int wav = tid >> 6;
    const int wm = wav >> 1, wn = wav & 1;
    const int fr = lane & 15;
    const int fks = (lane >> 4) << 3;

    f32x4 acc[2][2];
#pragma unroll
    for (int i = 0; i < 2; ++i)
#pragma unroll
        for (int j = 0; j < 2; ++j) acc[i][j] = (f32x4){0.f, 0.f, 0.f, 0.f};

#pragma unroll
    for (int kt = 0; kt < 256; kt += 32) {
        bf16x8 ah[2], al[2], bh[2], bl[2];
#pragma unroll
        for (int s = 0; s < 2; ++s) {
            ah[s] = *(const bf16x8*)&sAhi[(wm << 5) + (s << 4) + fr][kt + fks];
            al[s] = *(const bf16x8*)&sAlo[(wm << 5) + (s << 4) + fr][kt + fks];
            bh[s] = *(const bf16x8*)&sBhi[(wn << 5) + (s << 4) + fr][kt + fks];
            bl[s] = *(const bf16x8*)&sBlo[(wn << 5) + (s << 4) + fr][kt + fks];
        }
#pragma unroll
        for (int i = 0; i < 2; ++i)
#pragma unroll
            for (int j = 0; j < 2; ++j) {
                acc[i][j] = __builtin_amdgcn_mfma_f32_16x16x32_bf16(ah[i], bh[j], acc[i][j], 0, 0, 0);
                acc[i][j] = __builtin_amdgcn_mfma_f32_16x16x32_bf16(ah[i], bl[j], acc[i][j], 0, 0, 0);
                acc[i][j] = __builtin_amdgcn_mfma_f32_16x16x32_bf16(al[i], bh[j], acc[i][j], 0, 0, 0);
            }
    }

    const int rbase = (lane >> 4) << 2;
    if (!is_nt) {
#pragma unroll
        for (int i = 0; i < 2; ++i)
#pragma unroll
            for (int j = 0; j < 2; ++j) {
                const int gcol = n0 + (wn << 5) + (j << 4) + fr;
                const float bias = b1[gcol];
#pragma unroll
                for (int q = 0; q < 4; ++q) {
                    const int grow = m0 + (wm << 5) + (i << 4) + rbase + q;
                    float x = acc[i][j][q] + bias;
                    x = 1.0f - 2.0f * __builtin_amdgcn_rcpf(
                                          1.0f + __builtin_amdgcn_exp2f(C2F * x));
                    h1[(size_t)grow * 256 + gcol] = x;
                }
            }
    } else {
#pragma unroll
        for (int i = 0; i < 2; ++i)
#pragma unroll
            for (int j = 0; j < 2; ++j) {
                const int gcol = n0 + (wn << 5) + (j << 4) + fr;
#pragma unroll
                for (int q = 0; q < 4; ++q) {
                    const int grow = m0 + (wm << 5) + (i << 4) + rbase + q;
                    Wc[(size_t)grow * 256 + gcol] = acc[i][j][q];
                }
            }
        if ((blk & 3) == 0) {
            const int rr = tid >> 2;
            const int part = (tid & 3) << 6;
            const int grow = m0 + rr;
            const float* Ar = (grow < 256) ? &Wq[(size_t)grow * 256]
                                           : &Wk[(size_t)(grow - 256) * 256];
            float s = 0.f;
#pragma unroll
            for (int e = 0; e < 64; e += 4) {
                f4 a = *(const f4*)&Ar[part + e];
                f4 bv = *(const f4*)&b2[part + e];
                s += a[0] * bv[0] + a[1] * bv[1] + a[2] * bv[2] + a[3] * bv[3];
            }
            sred[rr][tid & 3] = s;
            __syncthreads();
            if (tid < 64) {
                float bias = sred[tid][0] + sred[tid][1] + sred[tid][2] + sred[tid][3];
                const int g2 = m0 + tid;
                bias += (g2 < 256) ? bq[g2] : bk[g2 - 256];
                bc[g2] = bias;
            }
        }
    }
}

// ---------------------------------------------------------------------------
// pairwise: per (b, i-tile, j-tile, 64-h chunk) block accumulates over two
// 32-h phases:  Ep[chunk][b,i,j] = sum_{h in 64-chunk} v_h/(1+u_ih w_jh)
// 256 thr, 64x64 tile, 4x4 per-thread outputs, LDS 2x[64][34] = 17.4 KB.
// __launch_bounds__(256,8): 8 blocks/CU -> VGPR cap 64, 32 waves/CU.
// (512,8) previously pinned VGPR=32 -> 180MB scratch spill; (512,4) capped
// at 128 VGPR = only 16 waves/CU.  All inner LDS reads are broadcast.
// ---------------------------------------------------------------------------
__global__ __launch_bounds__(256, 8) void pairwise_kernel(
    const float* __restrict__ uwb, const float* __restrict__ v,
    float* __restrict__ Ep) {
    __shared__ float sU[64][34];
    __shared__ float sW[64][34];
    __shared__ float sV[64];

    const int tid = threadIdx.x;
    const int bb = blockIdx.x;       // 1024 = (4b * 64 tiles) * 4 h-chunks
    const int hcs = bb & 3;          // 64-h chunk index
    const int hc = hcs << 6;
    const int tt = bb >> 2;
    const int b = tt >> 6;
    const int i0 = ((tt >> 3) & 7) << 6;
    const int j0 = (tt & 7) << 6;

    const float* ubase = uwb + (size_t)((b << 9) + i0) * 512 + hc;
    const float* wbase = uwb + (size_t)((b << 9) + j0) * 512 + 256 + hc;

    const int srow = tid >> 2;         // 0..63
    const int scol = (tid & 3) << 3;   // 0,8,16,24

    if (tid < 16) *(f4*)&sV[tid << 2] = *(const f4*)&v[hc + (tid << 2)];

    const int ty = tid >> 4;   // 0..15: rows ty+16d
    const int tx = tid & 15;   // 0..15: cols tx+16e

    float acc[4][4];
#pragma unroll
    for (int d = 0; d < 4; ++d)
#pragma unroll
        for (int e = 0; e < 4; ++e) acc[d][e] = 0.f;

    const f2 one2 = (f2){1.f, 1.f};

#pragma unroll
    for (int ph = 0; ph < 2; ++ph) {
        const int hb = ph << 5;
        // stage this 64x32 sub-chunk of u and w
        *(f4*)&sU[srow][scol]     = *(const f4*)&ubase[(size_t)srow * 512 + hb + scol];
        *(f4*)&sU[srow][scol + 4] = *(const f4*)&ubase[(size_t)srow * 512 + hb + scol + 4];
        *(f4*)&sW[srow][scol]     = *(const f4*)&wbase[(size_t)srow * 512 + hb + scol];
        *(f4*)&sW[srow][scol + 4] = *(const f4*)&wbase[(size_t)srow * 512 + hb + scol + 4];
        __syncthreads();

#pragma unroll 2
        for (int h4 = 0; h4 < 32; h4 += 4) {
            f4 vv = *(const f4*)&sV[hb + h4];
            f4 ww[4];
#pragma unroll
            for (int e = 0; e < 4; ++e)
                ww[e] = *(const f4*)&sW[tx + (e << 4)][h4];
#pragma unroll
            for (int d = 0; d < 4; ++d) {
                f4 uu = *(const f4*)&sU[ty + (d << 4)][h4];
                f2 u01 = (f2){uu[0], uu[1]};
                f2 u23 = (f2){uu[2], uu[3]};
#pragma unroll
                for (int e = 0; e < 4; ++e) {
                    f2 w01 = (f2){ww[e][0], ww[e][1]};
                    f2 w23 = (f2){ww[e][2], ww[e][3]};
                    f2 A01 = __builtin_elementwise_fma(u01, w01, one2);
                    f2 A23 = __builtin_elementwise_fma(u23, w23, one2);
                    float m01 = A01.x * A01.y;
                    float t01 = fmaf(vv[0], A01.y, vv[1] * A01.x);
                    acc[d][e] = fmaf(t01, __builtin_amdgcn_rcpf(m01), acc[d][e]);
                    float m23 = A23.x * A23.y;
                    float t23 = fmaf(vv[2], A23.y, vv[3] * A23.x);
                    acc[d][e] = fmaf(t23, __builtin_amdgcn_rcpf(m23), acc[d][e]);
                }
            }
        }
        __syncthreads();
    }

    float* ep = Ep + (size_t)hcs * 1048576 + (size_t)((b << 9) + i0) * 512 + j0;
#pragma unroll
    for (int d = 0; d < 4; ++d)
#pragma unroll
        for (int e = 0; e < 4; ++e)
            ep[(size_t)(ty + (d << 4)) * 512 + tx + (e << 4)] = acc[d][e];
}

// out[b,i,j] = Sv - sum_s Ep_s[b,i,j] - sum_s Ep_s[b,j,i]
__global__ __launch_bounds__(256) void sym_kernel(const float* __restrict__ Ep,
                                                  const float* __restrict__ v,
                                                  float* __restrict__ out) {
    __shared__ float t1[64][65];
    __shared__ float t2[64][65];
    __shared__ float red[4];

    const int tid = threadIdx.x;
    const int lane = tid & 63, wv = tid >> 6;

    float x = v[tid];
#pragma unroll
    for (int o = 32; o > 0; o >>= 1) x += __shfl_xor(x, o, 64);
    if (lane == 0) red[wv] = x;

    const int bb = blockIdx.x;
    const int b = bb >> 6;
    const int i0 = ((bb >> 3) & 7) << 6;
    const int j0 = (bb & 7) << 6;

    for (int idx = tid; idx < 4096; idx += 256) {
        const int r = idx >> 6, c = idx & 63;
        const size_t o1 = (size_t)((b << 9) + i0 + r) * 512 + j0 + c;
        const size_t o2 = (size_t)((b << 9) + j0 + r) * 512 + i0 + c;
        t1[r][c] = (Ep[o1] + Ep[o1 + 1048576]) +
                   (Ep[o1 + 2097152] + Ep[o1 + 3145728]);
        t2[r][c] = (Ep[o2] + Ep[o2 + 1048576]) +
                   (Ep[o2 + 2097152] + Ep[o2 + 3145728]);
    }
    __syncthreads();
    const float Sv = red[0] + red[1] + red[2] + red[3];
    for (int idx = tid; idx < 4096; idx += 256) {
        const int r = idx >> 6, c = idx & 63;
        out[(size_t)((b << 9) + i0 + r) * 512 + j0 + c] = Sv - (t1[r][c] + t2[c][r]);
    }
}

extern "C" void kernel_launch(void* const* d_in, const int* in_sizes, int n_in,
                              void* d_out, int out_size, void* d_ws, size_t ws_size,
                              hipStream_t stream) {
    const float* X  = (const float*)d_in[0];
    // d_in[1] = Y (unused)
    const float* W1 = (const float*)d_in[2];
    const float* b1 = (const float*)d_in[3];
    const float* W2 = (const float*)d_in[4];
    const float* b2 = (const float*)d_in[5];
    const float* Wq = (const float*)d_in[6];
    const float* bq = (const float*)d_in[7];
    const float* Wk = (const float*)d_in[8];
    const float* bk = (const float*)d_in[9];
    const float* v  = (const float*)d_in[10];
    // d_in[11] = k (unused)

    float* ws  = (float*)d_ws;
    float* h1  = ws;                 // 2048*256 = 524288 f
    float* uwb = ws + 524288;        // 2048*512 = 1048576 f
    float* Wc  = ws + 1572864;       // 512*256  = 131072 f
    float* bc  = ws + 1703936;       // 512 f
    float* Ep  = ws + 1704448;       // 4*1048576 f
    float* out = (float*)d_out;

    // fused: h1 = tanh(X@W1^T+b1)  and  Wc = [Wq;Wk]@W2, bc = [..]@b2 + bias
    gemm_stage1<<<160, 256, 0, stream>>>(X, W1, b1, Wq, Wk, W2, b2, bq, bk,
                                         h1, Wc, bc);
    // uwb[:, :256] = min(exp2(C2*Q),1e4), uwb[:, 256:] = min(exp2(C2*K),1e4)
    gemm_fullk<2><<<dim3(32, 8), 256, 0, stream>>>(h1, Wc, Wc + 65536, bc,
                                                   bc + 256, uwb, 512);
    // Ep[hc][b,i,j] = sum_{h in 64-chunk} v_h/(1+u w)
    pairwise_kernel<<<1024, 256, 0, stream>>>(uwb, v, Ep);
    // out = Sv - sum(Ep) - sum(Ep)^T
    sym_kernel<<<256, 256, 0, stream>>>(Ep, v, out);
}

// Round 8
// 63.204 us; speedup vs baseline: 1.0803x; 1.0803x over previous
//
#include <hip/hip_runtime.h>

// Problem: B=4, N=512, D=256, H=256, M = B*N = 2048
// out[b,i,j] = 0.5*(E + E^T),  E[b,i,j] = sum_h v[h]*tanh(Q[b,i,h]+K[b,j,h])
// tanh(q+k) = 1 - 2/(1+e^{2q}e^{2k}); u=exp2(C2*q), w=exp2(C2*k), C2=2*log2(e)
// P_ij = sum_h v_h/(1+u_ih w_jh);  out_ij = Sv - (P_ij + P_ji)
// 4-term batching (2 rcp per 8 terms), packed-f32 SoA:
//   pair i: A_e=1+u_e w_e, A_o=1+u_o w_o; m_i=A_e A_o; t_i=v_e A_o + v_o A_e
//   S(pair i,i+1) = (t_i m_{i+1} + t_{i+1} m_i)/(m_i m_{i+1})
//   u,w clamped <=1e4 in gemm3 -> A<=1e8, m*m<=1e32 (safe in fp32).
// u,w stored DEINTERLEAVED by h parity (even plane cols [0,128), odd [128,256)
// within each 256-col half of uwb) so pk ops get natural register pairs.
// GEMM fold: Q = h1 @ (Wq@W2)^T + (Wq@b2+bq)

typedef float f2 __attribute__((ext_vector_type(2)));
typedef float f4 __attribute__((ext_vector_type(4)));
typedef float f32x4 __attribute__((ext_vector_type(4)));
typedef __bf16 bf16x8 __attribute__((ext_vector_type(8)));

#define C2F 2.8853900817779268f

__device__ inline unsigned short f2bf(float f) {
    unsigned u = __float_as_uint(f);
    unsigned r = (u + 0x7fffu + ((u >> 16) & 1u)) >> 16;
    return (unsigned short)r;
}
__device__ inline float bf2f(unsigned short h) {
    return __uint_as_float(((unsigned)h) << 16);
}

__device__ inline void split4(const f4 a, unsigned short* hp, unsigned short* lp) {
    unsigned short h[4], l[4];
#pragma unroll
    for (int t = 0; t < 4; ++t) {
        h[t] = f2bf(a[t]);
        l[t] = f2bf(a[t] - bf2f(h[t]));
    }
    uint2 hv, lv;
    hv.x = (unsigned)h[0] | ((unsigned)h[1] << 16);
    hv.y = (unsigned)h[2] | ((unsigned)h[3] << 16);
    lv.x = (unsigned)l[0] | ((unsigned)l[1] << 16);
    lv.y = (unsigned)l[2] | ((unsigned)l[3] << 16);
    *(uint2*)hp = hv;
    *(uint2*)lp = lv;
}

// ---------------------------------------------------------------------------
// gemm_fullk: C[m,n] = act( sum_k A[m,k]*Wsel[n,k] + bias[n] ), K=256 resident.
// ACT: 1=tanh, 2=exp2(C2*x) clamped to [0,1e4], stored h-parity-deinterleaved.
// ---------------------------------------------------------------------------
template <int ACT>
__global__ __launch_bounds__(256) void gemm_fullk(
    const float* __restrict__ A, const float* __restrict__ Wa,
    const float* __restrict__ Wb, const float* __restrict__ ba,
    const float* __restrict__ bb2, float* __restrict__ C, int Nn) {
    __shared__ unsigned short sAhi[64][264];
    __shared__ unsigned short sAlo[64][264];
    __shared__ unsigned short sBhi[64][264];
    __shared__ unsigned short sBlo[64][264];

    const int tid = threadIdx.x;
    const int m0 = blockIdx.x << 6;
    const int n0 = blockIdx.y << 6;

    const float* Atile = A + (size_t)m0 * 256;
    const float* Wtile = (n0 < 256) ? (Wa + (size_t)n0 * 256)
                                    : (Wb + (size_t)(n0 - 256) * 256);
    const int col4 = (tid & 63) << 2;
    const int rgrp = tid >> 6;
#pragma unroll
    for (int t = 0; t < 16; ++t) {
        const int row = (t << 2) + rgrp;
        f4 av = *(const f4*)&Atile[(size_t)row * 256 + col4];
        f4 wv = *(const f4*)&Wtile[(size_t)row * 256 + col4];
        split4(av, &sAhi[row][col4], &sAlo[row][col4]);
        split4(wv, &sBhi[row][col4], &sBlo[row][col4]);
    }
    __syncthreads();

    const int lane = tid & 63;
    const int wav = tid >> 6;
    const int wm = wav >> 1, wn = wav & 1;
    const int fr = lane & 15;
    const int fks = (lane >> 4) << 3;

    f32x4 acc[2][2];
#pragma unroll
    for (int i = 0; i < 2; ++i)
#pragma unroll
        for (int j = 0; j < 2; ++j) acc[i][j] = (f32x4){0.f, 0.f, 0.f, 0.f};

#pragma unroll
    for (int kt = 0; kt < 256; kt += 32) {
        bf16x8 ah[2], al[2], bh[2], bl[2];
#pragma unroll
        for (int s = 0; s < 2; ++s) {
            ah[s] = *(const bf16x8*)&sAhi[(wm << 5) + (s << 4) + fr][kt + fks];
            al[s] = *(const bf16x8*)&sAlo[(wm << 5) + (s << 4) + fr][kt + fks];
            bh[s] = *(const bf16x8*)&sBhi[(wn << 5) + (s << 4) + fr][kt + fks];
            bl[s] = *(const bf16x8*)&sBlo[(wn << 5) + (s << 4) + fr][kt + fks];
        }
#pragma unroll
        for (int i = 0; i < 2; ++i)
#pragma unroll
            for (int j = 0; j < 2; ++j) {
                acc[i][j] = __builtin_amdgcn_mfma_f32_16x16x32_bf16(ah[i], bh[j], acc[i][j], 0, 0, 0);
                acc[i][j] = __builtin_amdgcn_mfma_f32_16x16x32_bf16(ah[i], bl[j], acc[i][j], 0, 0, 0);
                acc[i][j] = __builtin_amdgcn_mfma_f32_16x16x32_bf16(al[i], bh[j], acc[i][j], 0, 0, 0);
            }
    }

    const int rbase = (lane >> 4) << 2;
#pragma unroll
    for (int i = 0; i < 2; ++i) {
#pragma unroll
        for (int j = 0; j < 2; ++j) {
            const int gcol = n0 + (wn << 5) + (j << 4) + fr;
            const float bias = (ACT == 2 && gcol >= 256) ? bb2[gcol - 256] : ba[gcol];
            // deinterleaved store column for ACT==2
            int scol = gcol;
            if (ACT == 2) {
                const int half = gcol & 256;          // 0 for u, 256 for w
                const int c = gcol & 255;
                scol = half + ((c & 1) << 7) + (c >> 1);
            }
#pragma unroll
            for (int q = 0; q < 4; ++q) {
                const int grow = m0 + (wm << 5) + (i << 4) + rbase + q;
                float x = acc[i][j][q] + bias;
                if (ACT == 1)
                    x = 1.0f - 2.0f * __builtin_amdgcn_rcpf(
                                          1.0f + __builtin_amdgcn_exp2f(C2F * x));
                if (ACT == 2)
                    x = fminf(__builtin_amdgcn_exp2f(C2F * x), 1.0e4f);
                C[(size_t)grow * Nn + scol] = x;
            }
        }
    }
}

// ---------------------------------------------------------------------------
// gemm_stage1: fused launch.
//  blocks [0,128): h1 = tanh(X @ W1^T + b1)
//  blocks [128,160): Wc = [Wq;Wk] @ W2 (B not transp.), bc = Asel@b2 + bias
// ---------------------------------------------------------------------------
__global__ __launch_bounds__(256) void gemm_stage1(
    const float* __restrict__ X, const float* __restrict__ W1,
    const float* __restrict__ b1, const float* __restrict__ Wq,
    const float* __restrict__ Wk, const float* __restrict__ W2,
    const float* __restrict__ b2, const float* __restrict__ bq,
    const float* __restrict__ bk, float* __restrict__ h1,
    float* __restrict__ Wc, float* __restrict__ bc) {
    __shared__ unsigned short sAhi[64][264];
    __shared__ unsigned short sAlo[64][264];
    __shared__ unsigned short sBhi[64][264];
    __shared__ unsigned short sBlo[64][264];
    __shared__ float sred[64][4];

    const int tid = threadIdx.x;
    const bool is_nt = (blockIdx.x >= 128);
    const int blk = is_nt ? (blockIdx.x - 128) : blockIdx.x;
    const int m0 = (blk >> 2) << 6;
    const int n0 = (blk & 3) << 6;

    const int col4 = (tid & 63) << 2;
    const int rgrp = tid >> 6;

    if (!is_nt) {
        const float* Atile = X + (size_t)m0 * 256;
        const float* Wtile = W1 + (size_t)n0 * 256;
#pragma unroll
        for (int t = 0; t < 16; ++t) {
            const int row = (t << 2) + rgrp;
            f4 av = *(const f4*)&Atile[(size_t)row * 256 + col4];
            f4 wv = *(const f4*)&Wtile[(size_t)row * 256 + col4];
            split4(av, &sAhi[row][col4], &sAlo[row][col4]);
            split4(wv, &sBhi[row][col4], &sBlo[row][col4]);
        }
    } else {
        const float* Atile = (m0 < 256) ? (Wq + (size_t)m0 * 256)
                                        : (Wk + (size_t)(m0 - 256) * 256);
#pragma unroll
        for (int t = 0; t < 16; ++t) {
            const int row = (t << 2) + rgrp;
            f4 av = *(const f4*)&Atile[(size_t)row * 256 + col4];
            split4(av, &sAhi[row][col4], &sAlo[row][col4]);
        }
        const int c4 = (tid & 15) << 2;
        const int kg = tid >> 4;
#pragma unroll
        for (int t = 0; t < 16; ++t) {
            const int k = (t << 4) + kg;
            f4 wv = *(const f4*)&W2[(size_t)k * 256 + n0 + c4];
#pragma unroll
            for (int q = 0; q < 4; ++q) {
                unsigned short hi = f2bf(wv[q]);
                sBhi[c4 + q][k] = hi;
                sBlo[c4 + q][k] = f2bf(wv[q] - bf2f(hi));
            }
        }
    }
    __syncthreads();

    const int lane = tid & 63;
    const int wav = tid >> 6;
    const int wm = wav >> 1, wn = wav & 1;
    const int fr = lane & 15;
    const int fks = (lane >> 4) << 3;

    f32x4 acc[2][2];
#pragma unroll
    for (int i = 0; i < 2; ++i)
#pragma unroll
        for (int j = 0; j < 2; ++j) acc[i][j] = (f32x4){0.f, 0.f, 0.f, 0.f};

#pragma unroll
    for (int kt = 0; kt < 256; kt += 32) {
        bf16x8 ah[2], al[2], bh[2], bl[2];
#pragma unroll
        for (int s = 0; s < 2; ++s) {
            ah[s] = *(const bf16x8*)&sAhi[(wm << 5) + (s << 4) + fr][kt + fks];
            al[s] = *(const bf16x8*)&sAlo[(wm << 5) + (s << 4) + fr][kt + fks];
            bh[s] = *(const bf16x8*)&sBhi[(wn << 5) + (s << 4) + fr][kt + fks];
            bl[s] = *(const bf16x8*)&sBlo[(wn << 5) + (s << 4) + fr][kt + fks];
        }
#pragma unroll
        for (int i = 0; i < 2; ++i)
#pragma unroll
            for (int j = 0; j < 2; ++j) {
                acc[i][j] = __builtin_amdgcn_mfma_f32_16x16x32_bf16(ah[i], bh[j], acc[i][j], 0, 0, 0);
                acc[i][j] = __builtin_amdgcn_mfma_f32_16x16x32_bf16(ah[i], bl[j], acc[i][j], 0, 0, 0);
                acc[i][j] = __builtin_amdgcn_mfma_f32_16x16x32_bf16(al[i], bh[j], acc[i][j], 0, 0, 0);
            }
    }

    const int rbase = (lane >> 4) << 2;
    if (!is_nt) {
#pragma unroll
        for (int i = 0; i < 2; ++i)
#pragma unroll
            for (int j = 0; j < 2; ++j) {
                const int gcol = n0 + (wn << 5) + (j << 4) + fr;
                const float bias = b1[gcol];
#pragma unroll
                for (int q = 0; q < 4; ++q) {
                    const int grow = m0 + (wm << 5) + (i << 4) + rbase + q;
                    float x = acc[i][j][q] + bias;
                    x = 1.0f - 2.0f * __builtin_amdgcn_rcpf(
                                          1.0f + __builtin_amdgcn_exp2f(C2F * x));
                    h1[(size_t)grow * 256 + gcol] = x;
                }
            }
    } else {
#pragma unroll
        for (int i = 0; i < 2; ++i)
#pragma unroll
            for (int j = 0; j < 2; ++j) {
                const int gcol = n0 + (wn << 5) + (j << 4) + fr;
#pragma unroll
                for (int q = 0; q < 4; ++q) {
                    const int grow = m0 + (wm << 5) + (i << 4) + rbase + q;
                    Wc[(size_t)grow * 256 + gcol] = acc[i][j][q];
                }
            }
        if ((blk & 3) == 0) {
            const int rr = tid >> 2;
            const int part = (tid & 3) << 6;
            const int grow = m0 + rr;
            const float* Ar = (grow < 256) ? &Wq[(size_t)grow * 256]
                                           : &Wk[(size_t)(grow - 256) * 256];
            float s = 0.f;
#pragma unroll
            for (int e = 0; e < 64; e += 4) {
                f4 a = *(const f4*)&Ar[part + e];
                f4 bv = *(const f4*)&b2[part + e];
                s += a[0] * bv[0] + a[1] * bv[1] + a[2] * bv[2] + a[3] * bv[3];
            }
            sred[rr][tid & 3] = s;
            __syncthreads();
            if (tid < 64) {
                float bias = sred[tid][0] + sred[tid][1] + sred[tid][2] + sred[tid][3];
                const int g2 = m0 + tid;
                bias += (g2 < 256) ? bq[g2] : bk[g2 - 256];
                bc[g2] = bias;
            }
        }
    }
}

// ---------------------------------------------------------------------------
// pairwise: per (b, i-tile, j-tile, 64-h chunk) block:
//   Ep[chunk][b,i,j] = sum_{h in chunk} v_h/(1+u_ih w_jh)
// 512 thr, 64x64 tile, 4x2 outputs/thread.  u,w read from parity-deinterleaved
// planes; packed-f32 math; 2 rcp per 8 terms.  LDS 4x[64][36] = 37 KB.
// ---------------------------------------------------------------------------
__global__ __launch_bounds__(512, 4) void pairwise_kernel(
    const float* __restrict__ uwb, const float* __restrict__ v,
    float* __restrict__ Ep) {
    __shared__ float sUe[64][36];
    __shared__ float sUo[64][36];
    __shared__ float sWe[64][36];
    __shared__ float sWo[64][36];
    __shared__ float sVe[32];
    __shared__ float sVo[32];

    const int tid = threadIdx.x;
    const int bb = blockIdx.x;       // 1024 = (4b * 64 tiles) * 4 h-chunks
    const int hcs = bb & 3;
    const int tt = bb >> 2;
    const int b = tt >> 6;
    const int i0 = ((tt >> 3) & 7) << 6;
    const int j0 = (tt & 7) << 6;

    // even plane cols [0,128), odd [128,256) within each half; chunk -> +32*hcs
    const float* ub = uwb + (size_t)((b << 9) + i0) * 512 + (hcs << 5);
    const float* wb = uwb + (size_t)((b << 9) + j0) * 512 + 256 + (hcs << 5);

    const int row = tid >> 3;          // 0..63
    const int c4 = (tid & 7) << 2;     // 0,4,..,28
    *(f4*)&sUe[row][c4] = *(const f4*)&ub[(size_t)row * 512 + c4];
    *(f4*)&sUo[row][c4] = *(const f4*)&ub[(size_t)row * 512 + 128 + c4];
    *(f4*)&sWe[row][c4] = *(const f4*)&wb[(size_t)row * 512 + c4];
    *(f4*)&sWo[row][c4] = *(const f4*)&wb[(size_t)row * 512 + 128 + c4];
    if (tid < 32) {
        sVe[tid] = v[(hcs << 6) + (tid << 1)];
        sVo[tid] = v[(hcs << 6) + (tid << 1) + 1];
    }
    __syncthreads();

    const int ty = tid >> 5;   // 0..15: rows ty+16d
    const int tx = tid & 31;   // 0..31: cols tx+32e

    f2 acc[4][2];
#pragma unroll
    for (int d = 0; d < 4; ++d)
#pragma unroll
        for (int e = 0; e < 2; ++e) acc[d][e] = (f2){0.f, 0.f};

    const f2 one2 = (f2){1.f, 1.f};

#pragma unroll 2
    for (int g = 0; g < 8; ++g) {
        const int hb = g << 2;
        const f4 ve = *(const f4*)&sVe[hb];
        const f4 vo = *(const f4*)&sVo[hb];
        f4 we[2], wo[2];
#pragma unroll
        for (int e = 0; e < 2; ++e) {
            we[e] = *(const f4*)&sWe[tx + (e << 5)][hb];
            wo[e] = *(const f4*)&sWo[tx + (e << 5)][hb];
        }
#pragma unroll
        for (int d = 0; d < 4; ++d) {
            const f4 ue = *(const f4*)&sUe[ty + (d << 4)][hb];
            const f4 uo = *(const f4*)&sUo[ty + (d << 4)][hb];
            const f2 ue_lo = (f2){ue.x, ue.y}, ue_hi = (f2){ue.z, ue.w};
            const f2 uo_lo = (f2){uo.x, uo.y}, uo_hi = (f2){uo.z, uo.w};
#pragma unroll
            for (int e = 0; e < 2; ++e) {
                const f2 we_lo = (f2){we[e].x, we[e].y}, we_hi = (f2){we[e].z, we[e].w};
                const f2 wo_lo = (f2){wo[e].x, wo[e].y}, wo_hi = (f2){wo[e].z, wo[e].w};
                // A's (packed over pair index)
                f2 Ae1 = __builtin_elementwise_fma(ue_lo, we_lo, one2); // [A_e p0, A_e p1]
                f2 Ao1 = __builtin_elementwise_fma(uo_lo, wo_lo, one2);
                f2 Ae2 = __builtin_elementwise_fma(ue_hi, we_hi, one2); // pairs 2,3
                f2 Ao2 = __builtin_elementwise_fma(uo_hi, wo_hi, one2);
                // per-pair m and t (packed)
                f2 mlo = Ae1 * Ao1;                       // [m0, m1]
                f2 mhi = Ae2 * Ao2;                       // [m2, m3]
                f2 tlo = __builtin_elementwise_fma(
                    (f2){ve.x, ve.y}, Ao1, (f2){vo.x, vo.y} * Ae1);  // [t0, t1]
                f2 thi = __builtin_elementwise_fma(
                    (f2){ve.z, ve.w}, Ao2, (f2){vo.z, vo.w} * Ae2);  // [t2, t3]
                // level-2 combine (scalar)
                float Mlo = mlo.x * mlo.y;
                float Nlo = fmaf(tlo.x, mlo.y, tlo.y * mlo.x);
                float Mhi = mhi.x * mhi.y;
                float Nhi = fmaf(thi.x, mhi.y, thi.y * mhi.x);
                acc[d][e].x = fmaf(Nlo, __builtin_amdgcn_rcpf(Mlo), acc[d][e].x);
                acc[d][e].y = fmaf(Nhi, __builtin_amdgcn_rcpf(Mhi), acc[d][e].y);
            }
        }
    }

    float* ep = Ep + (size_t)hcs * 1048576 + (size_t)((b << 9) + i0) * 512 + j0;
#pragma unroll
    for (int d = 0; d < 4; ++d)
#pragma unroll
        for (int e = 0; e < 2; ++e)
            ep[(size_t)(ty + (d << 4)) * 512 + tx + (e << 5)] =
                acc[d][e].x + acc[d][e].y;
}

// out[b,i,j] = Sv - sum_s Ep_s[b,i,j] - sum_s Ep_s[b,j,i]
__global__ __launch_bounds__(256) void sym_kernel(const float* __restrict__ Ep,
                                                  const float* __restrict__ v,
                                                  float* __restrict__ out) {
    __shared__ float t1[64][65];
    __shared__ float t2[64][65];
    __shared__ float red[4];

    const int tid = threadIdx.x;
    const int lane = tid & 63, wv = tid >> 6;

    float x = v[tid];
#pragma unroll
    for (int o = 32; o > 0; o >>= 1) x += __shfl_xor(x, o, 64);
    if (lane == 0) red[wv] = x;

    const int bb = blockIdx.x;
    const int b = bb >> 6;
    const int i0 = ((bb >> 3) & 7) << 6;
    const int j0 = (bb & 7) << 6;

    for (int idx = tid; idx < 4096; idx += 256) {
        const int r = idx >> 6, c = idx & 63;
        const size_t o1 = (size_t)((b << 9) + i0 + r) * 512 + j0 + c;
        const size_t o2 = (size_t)((b << 9) + j0 + r) * 512 + i0 + c;
        t1[r][c] = (Ep[o1] + Ep[o1 + 1048576]) +
                   (Ep[o1 + 2097152] + Ep[o1 + 3145728]);
        t2[r][c] = (Ep[o2] + Ep[o2 + 1048576]) +
                   (Ep[o2 + 2097152] + Ep[o2 + 3145728]);
    }
    __syncthreads();
    const float Sv = red[0] + red[1] + red[2] + red[3];
    for (int idx = tid; idx < 4096; idx += 256) {
        const int r = idx >> 6, c = idx & 63;
        out[(size_t)((b << 9) + i0 + r) * 512 + j0 + c] = Sv - (t1[r][c] + t2[c][r]);
    }
}

extern "C" void kernel_launch(void* const* d_in, const int* in_sizes, int n_in,
                              void* d_out, int out_size, void* d_ws, size_t ws_size,
                              hipStream_t stream) {
    const float* X  = (const float*)d_in[0];
    // d_in[1] = Y (unused)
    const float* W1 = (const float*)d_in[2];
    const float* b1 = (const float*)d_in[3];
    const float* W2 = (const float*)d_in[4];
    const float* b2 = (const float*)d_in[5];
    const float* Wq = (const float*)d_in[6];
    const float* bq = (const float*)d_in[7];
    const float* Wk = (const float*)d_in[8];
    const float* bk = (const float*)d_in[9];
    const float* v  = (const float*)d_in[10];
    // d_in[11] = k (unused)

    float* ws  = (float*)d_ws;
    float* h1  = ws;                 // 2048*256 = 524288 f
    float* uwb = ws + 524288;        // 2048*512 = 1048576 f (deinterleaved)
    float* Wc  = ws + 1572864;       // 512*256  = 131072 f
    float* bc  = ws + 1703936;       // 512 f
    float* Ep  = ws + 1704448;       // 4*1048576 f
    float* out = (float*)d_out;

    // fused: h1 = tanh(X@W1^T+b1)  and  Wc = [Wq;Wk]@W2, bc = [..]@b2 + bias
    gemm_stage1<<<160, 256, 0, stream>>>(X, W1, b1, Wq, Wk, W2, b2, bq, bk,
                                         h1, Wc, bc);
    // uwb = deinterleaved min(exp2(C2*Q),1e4) | min(exp2(C2*K),1e4)
    gemm_fullk<2><<<dim3(32, 8), 256, 0, stream>>>(h1, Wc, Wc + 65536, bc,
                                                   bc + 256, uwb, 512);
    // Ep[hc][b,i,j] = sum_{h in 64-chunk} v_h/(1+u w)
    pairwise_kernel<<<1024, 512, 0, stream>>>(uwb, v, Ep);
    // out = Sv - sum(Ep) - sum(Ep)^T
    sym_kernel<<<256, 256, 0, stream>>>(Ep, v, out);
}

// Round 9
// 62.627 us; speedup vs baseline: 1.0902x; 1.0092x over previous
//
#include <hip/hip_runtime.h>

// Problem: B=4, N=512, D=256, H=256, M = B*N = 2048
// out[b,i,j] = 0.5*(E + E^T),  E[b,i,j] = sum_h v[h]*tanh(Q[b,i,h]+K[b,j,h])
// tanh(q+k) = 1 - 2/(1+e^{2q}e^{2k}); u=exp2(C2*q), w=exp2(C2*k), C2=2*log2(e)
// P_ij = sum_h v_h/(1+u_ih w_jh);  out_ij = Sv - (P_ij + P_ji)
// 8-way rcp batching (1 rcp per 8 terms) via common-denominator tree:
//   leaves A_t; pairs (m,t); quads; oct -> N/M, sum8 = N*rcp(M).
// Overflow: u pre-scaled by 2^-8 in gemm epilogue (u' = exp2(C2*Q - 8), clamp 4;
//   w = exp2(C2*K), clamp 1024).  Leaf A' = fma(u',w,2^-8) = 2^-8*(1+uw).
//   M' = prod8 <= 4096^8 ~ 8e28 (safe); group sum = (N'/M')*2^-8 -> fold 2^-8
//   into the final store (one mul per output).
// GEMM fold: Q = h1 @ (Wq@W2)^T + (Wq@b2+bq)

typedef float f2 __attribute__((ext_vector_type(2)));
typedef float f4 __attribute__((ext_vector_type(4)));
typedef float f32x4 __attribute__((ext_vector_type(4)));
typedef __bf16 bf16x8 __attribute__((ext_vector_type(8)));

#define C2F 2.8853900817779268f
#define S8  0.00390625f   // 2^-8

__device__ inline unsigned short f2bf(float f) {
    unsigned u = __float_as_uint(f);
    unsigned r = (u + 0x7fffu + ((u >> 16) & 1u)) >> 16;
    return (unsigned short)r;
}
__device__ inline float bf2f(unsigned short h) {
    return __uint_as_float(((unsigned)h) << 16);
}

__device__ inline void split4(const f4 a, unsigned short* hp, unsigned short* lp) {
    unsigned short h[4], l[4];
#pragma unroll
    for (int t = 0; t < 4; ++t) {
        h[t] = f2bf(a[t]);
        l[t] = f2bf(a[t] - bf2f(h[t]));
    }
    uint2 hv, lv;
    hv.x = (unsigned)h[0] | ((unsigned)h[1] << 16);
    hv.y = (unsigned)h[2] | ((unsigned)h[3] << 16);
    lv.x = (unsigned)l[0] | ((unsigned)l[1] << 16);
    lv.y = (unsigned)l[2] | ((unsigned)l[3] << 16);
    *(uint2*)hp = hv;
    *(uint2*)lp = lv;
}

// ---------------------------------------------------------------------------
// gemm_fullk: C[m,n] = act( sum_k A[m,k]*Wsel[n,k] + bias[n] ), K=256 resident.
// ACT: 1=tanh, 2: col<256 -> min(exp2(C2*x-8),4); col>=256 -> min(exp2(C2*x),1024)
// ---------------------------------------------------------------------------
template <int ACT>
__global__ __launch_bounds__(256) void gemm_fullk(
    const float* __restrict__ A, const float* __restrict__ Wa,
    const float* __restrict__ Wb, const float* __restrict__ ba,
    const float* __restrict__ bb2, float* __restrict__ C, int Nn) {
    __shared__ unsigned short sAhi[64][264];
    __shared__ unsigned short sAlo[64][264];
    __shared__ unsigned short sBhi[64][264];
    __shared__ unsigned short sBlo[64][264];

    const int tid = threadIdx.x;
    const int m0 = blockIdx.x << 6;
    const int n0 = blockIdx.y << 6;

    const float* Atile = A + (size_t)m0 * 256;
    const float* Wtile = (n0 < 256) ? (Wa + (size_t)n0 * 256)
                                    : (Wb + (size_t)(n0 - 256) * 256);
    const int col4 = (tid & 63) << 2;
    const int rgrp = tid >> 6;
#pragma unroll
    for (int t = 0; t < 16; ++t) {
        const int row = (t << 2) + rgrp;
        f4 av = *(const f4*)&Atile[(size_t)row * 256 + col4];
        f4 wv = *(const f4*)&Wtile[(size_t)row * 256 + col4];
        split4(av, &sAhi[row][col4], &sAlo[row][col4]);
        split4(wv, &sBhi[row][col4], &sBlo[row][col4]);
    }
    __syncthreads();

    const int lane = tid & 63;
    const int wav = tid >> 6;
    const int wm = wav >> 1, wn = wav & 1;
    const int fr = lane & 15;
    const int fks = (lane >> 4) << 3;

    f32x4 acc[2][2];
#pragma unroll
    for (int i = 0; i < 2; ++i)
#pragma unroll
        for (int j = 0; j < 2; ++j) acc[i][j] = (f32x4){0.f, 0.f, 0.f, 0.f};

#pragma unroll
    for (int kt = 0; kt < 256; kt += 32) {
        bf16x8 ah[2], al[2], bh[2], bl[2];
#pragma unroll
        for (int s = 0; s < 2; ++s) {
            ah[s] = *(const bf16x8*)&sAhi[(wm << 5) + (s << 4) + fr][kt + fks];
            al[s] = *(const bf16x8*)&sAlo[(wm << 5) + (s << 4) + fr][kt + fks];
            bh[s] = *(const bf16x8*)&sBhi[(wn << 5) + (s << 4) + fr][kt + fks];
            bl[s] = *(const bf16x8*)&sBlo[(wn << 5) + (s << 4) + fr][kt + fks];
        }
#pragma unroll
        for (int i = 0; i < 2; ++i)
#pragma unroll
            for (int j = 0; j < 2; ++j) {
                acc[i][j] = __builtin_amdgcn_mfma_f32_16x16x32_bf16(ah[i], bh[j], acc[i][j], 0, 0, 0);
                acc[i][j] = __builtin_amdgcn_mfma_f32_16x16x32_bf16(ah[i], bl[j], acc[i][j], 0, 0, 0);
                acc[i][j] = __builtin_amdgcn_mfma_f32_16x16x32_bf16(al[i], bh[j], acc[i][j], 0, 0, 0);
            }
    }

    const int rbase = (lane >> 4) << 2;
#pragma unroll
    for (int i = 0; i < 2; ++i) {
#pragma unroll
        for (int j = 0; j < 2; ++j) {
            const int gcol = n0 + (wn << 5) + (j << 4) + fr;
            const float bias = (ACT == 2 && gcol >= 256) ? bb2[gcol - 256] : ba[gcol];
#pragma unroll
            for (int q = 0; q < 4; ++q) {
                const int grow = m0 + (wm << 5) + (i << 4) + rbase + q;
                float x = acc[i][j][q] + bias;
                if (ACT == 1)
                    x = 1.0f - 2.0f * __builtin_amdgcn_rcpf(
                                          1.0f + __builtin_amdgcn_exp2f(C2F * x));
                if (ACT == 2) {
                    if (gcol < 256)
                        x = fminf(__builtin_amdgcn_exp2f(C2F * x - 8.0f), 4.0f);
                    else
                        x = fminf(__builtin_amdgcn_exp2f(C2F * x), 1024.0f);
                }
                C[(size_t)grow * Nn + gcol] = x;
            }
        }
    }
}

// ---------------------------------------------------------------------------
// gemm_stage1: fused launch.
//  blocks [0,128): h1 = tanh(X @ W1^T + b1)
//  blocks [128,160): Wc = [Wq;Wk] @ W2 (B not transp.), bc = Asel@b2 + bias
// ---------------------------------------------------------------------------
__global__ __launch_bounds__(256) void gemm_stage1(
    const float* __restrict__ X, const float* __restrict__ W1,
    const float* __restrict__ b1, const float* __restrict__ Wq,
    const float* __restrict__ Wk, const float* __restrict__ W2,
    const float* __restrict__ b2, const float* __restrict__ bq,
    const float* __restrict__ bk, float* __restrict__ h1,
    float* __restrict__ Wc, float* __restrict__ bc) {
    __shared__ unsigned short sAhi[64][264];
    __shared__ unsigned short sAlo[64][264];
    __shared__ unsigned short sBhi[64][264];
    __shared__ unsigned short sBlo[64][264];
    __shared__ float sred[64][4];

    const int tid = threadIdx.x;
    const bool is_nt = (blockIdx.x >= 128);
    const int blk = is_nt ? (blockIdx.x - 128) : blockIdx.x;
    const int m0 = (blk >> 2) << 6;
    const int n0 = (blk & 3) << 6;

    const int col4 = (tid & 63) << 2;
    const int rgrp = tid >> 6;

    if (!is_nt) {
        const float* Atile = X + (size_t)m0 * 256;
        const float* Wtile = W1 + (size_t)n0 * 256;
#pragma unroll
        for (int t = 0; t < 16; ++t) {
            const int row = (t << 2) + rgrp;
            f4 av = *(const f4*)&Atile[(size_t)row * 256 + col4];
            f4 wv = *(const f4*)&Wtile[(size_t)row * 256 + col4];
            split4(av, &sAhi[row][col4], &sAlo[row][col4]);
            split4(wv, &sBhi[row][col4], &sBlo[row][col4]);
        }
    } else {
        const float* Atile = (m0 < 256) ? (Wq + (size_t)m0 * 256)
                                        : (Wk + (size_t)(m0 - 256) * 256);
#pragma unroll
        for (int t = 0; t < 16; ++t) {
            const int row = (t << 2) + rgrp;
            f4 av = *(const f4*)&Atile[(size_t)row * 256 + col4];
            split4(av, &sAhi[row][col4], &sAlo[row][col4]);
        }
        const int c4 = (tid & 15) << 2;
        const int kg = tid >> 4;
#pragma unroll
        for (int t = 0; t < 16; ++t) {
            const int k = (t << 4) + kg;
            f4 wv = *(const f4*)&W2[(size_t)k * 256 + n0 + c4];
#pragma unroll
            for (int q = 0; q < 4; ++q) {
                unsigned short hi = f2bf(wv[q]);
                sBhi[c4 + q][k] = hi;
                sBlo[c4 + q][k] = f2bf(wv[q] - bf2f(hi));
            }
        }
    }
    __syncthreads();

    const int lane = tid & 63;
    const int wav = tid >> 6;
    const int wm = wav >> 1, wn = wav & 1;
    const int fr = lane & 15;
    const int fks = (lane >> 4) << 3;

    f32x4 acc[2][2];
#pragma unroll
    for (int i = 0; i < 2; ++i)
#pragma unroll
        for (int j = 0; j < 2; ++j) acc[i][j] = (f32x4){0.f, 0.f, 0.f, 0.f};

#pragma unroll
    for (int kt = 0; kt < 256; kt += 32) {
        bf16x8 ah[2], al[2], bh[2], bl[2];
#pragma unroll
        for (int s = 0; s < 2; ++s) {
            ah[s] = *(const bf16x8*)&sAhi[(wm << 5) + (s << 4) + fr][kt + fks];
            al[s] = *(const bf16x8*)&sAlo[(wm << 5) + (s << 4) + fr][kt + fks];
            bh[s] = *(const bf16x8*)&sBhi[(wn << 5) + (s << 4) + fr][kt + fks];
            bl[s] = *(const bf16x8*)&sBlo[(wn << 5) + (s << 4) + fr][kt + fks];
        }
#pragma unroll
        for (int i = 0; i < 2; ++i)
#pragma unroll
            for (int j = 0; j < 2; ++j) {
                acc[i][j] = __builtin_amdgcn_mfma_f32_16x16x32_bf16(ah[i], bh[j], acc[i][j], 0, 0, 0);
                acc[i][j] = __builtin_amdgcn_mfma_f32_16x16x32_bf16(ah[i], bl[j], acc[i][j], 0, 0, 0);
                acc[i][j] = __builtin_amdgcn_mfma_f32_16x16x32_bf16(al[i], bh[j], acc[i][j], 0, 0, 0);
            }
    }

    const int rbase = (lane >> 4) << 2;
    if (!is_nt) {
#pragma unroll
        for (int i = 0; i < 2; ++i)
#pragma unroll
            for (int j = 0; j < 2; ++j) {
                const int gcol = n0 + (wn << 5) + (j << 4) + fr;
                const float bias = b1[gcol];
#pragma unroll
                for (int q = 0; q < 4; ++q) {
                    const int grow = m0 + (wm << 5) + (i << 4) + rbase + q;
                    float x = acc[i][j][q] + bias;
                    x = 1.0f - 2.0f * __builtin_amdgcn_rcpf(
                                          1.0f + __builtin_amdgcn_exp2f(C2F * x));
                    h1[(size_t)grow * 256 + gcol] = x;
                }
            }
    } else {
#pragma unroll
        for (int i = 0; i < 2; ++i)
#pragma unroll
            for (int j = 0; j < 2; ++j) {
                const int gcol = n0 + (wn << 5) + (j << 4) + fr;
#pragma unroll
                for (int q = 0; q < 4; ++q) {
                    const int grow = m0 + (wm << 5) + (i << 4) + rbase + q;
                    Wc[(size_t)grow * 256 + gcol] = acc[i][j][q];
                }
            }
        if ((blk & 3) == 0) {
            const int rr = tid >> 2;
            const int part = (tid & 3) << 6;
            const int grow = m0 + rr;
            const float* Ar = (grow < 256) ? &Wq[(size_t)grow * 256]
                                           : &Wk[(size_t)(grow - 256) * 256];
            float s = 0.f;
#pragma unroll
            for (int e = 0; e < 64; e += 4) {
                f4 a = *(const f4*)&Ar[part + e];
                f4 bv = *(const f4*)&b2[part + e];
                s += a[0] * bv[0] + a[1] * bv[1] + a[2] * bv[2] + a[3] * bv[3];
            }
            sred[rr][tid & 3] = s;
            __syncthreads();
            if (tid < 64) {
                float bias = sred[tid][0] + sred[tid][1] + sred[tid][2] + sred[tid][3];
                const int g2 = m0 + tid;
                bias += (g2 < 256) ? bq[g2] : bk[g2 - 256];
                bc[g2] = bias;
            }
        }
    }
}

// ---------------------------------------------------------------------------
// pairwise: per (b, i-tile, j-tile, 64-h chunk) block accumulates into Ep:
//   Ep[b,i,j] += sum_{h in chunk} v_h/(1+u_ih w_jh)       (atomicAdd, 4 chunks)
// 512 thr, 64x64 tile, 4x2 outputs/thread, 8-way rcp batching.
// ---------------------------------------------------------------------------
__global__ __launch_bounds__(512, 4) void pairwise_kernel(
    const float* __restrict__ uwb, const float* __restrict__ v,
    float* __restrict__ Ep) {
    __shared__ float sU[64][68];
    __shared__ float sW[64][68];
    __shared__ float sV[64];

    const int tid = threadIdx.x;
    const int bb = blockIdx.x;       // 1024 = (4b * 64 tiles) * 4 h-chunks
    const int hcs = bb & 3;
    const int hc = hcs << 6;
    const int tt = bb >> 2;
    const int b = tt >> 6;
    const int i0 = ((tt >> 3) & 7) << 6;
    const int j0 = (tt & 7) << 6;

    const float* ubase = uwb + (size_t)((b << 9) + i0) * 512 + hc;
    const float* wbase = uwb + (size_t)((b << 9) + j0) * 512 + 256 + hc;

    const int sr = tid >> 3;         // 0..63
    const int sc = (tid & 7) << 3;   // 0,8,..,56
    {
        f4 a0 = *(const f4*)&ubase[(size_t)sr * 512 + sc];
        f4 a1 = *(const f4*)&ubase[(size_t)sr * 512 + sc + 4];
        f4 b0 = *(const f4*)&wbase[(size_t)sr * 512 + sc];
        f4 b1 = *(const f4*)&wbase[(size_t)sr * 512 + sc + 4];
        *(f4*)&sU[sr][sc] = a0;
        *(f4*)&sU[sr][sc + 4] = a1;
        *(f4*)&sW[sr][sc] = b0;
        *(f4*)&sW[sr][sc + 4] = b1;
    }
    if (tid < 16) *(f4*)&sV[tid << 2] = *(const f4*)&v[hc + (tid << 2)];
    __syncthreads();

    const int ty = tid >> 5;   // 0..15: rows ty+16d
    const int tx = tid & 31;   // 0..31: cols tx+32e

    float acc[4][2];
#pragma unroll
    for (int d = 0; d < 4; ++d)
#pragma unroll
        for (int e = 0; e < 2; ++e) acc[d][e] = 0.f;

#pragma unroll 2
    for (int h8 = 0; h8 < 64; h8 += 8) {
        const f4 vv0 = *(const f4*)&sV[h8];
        const f4 vv1 = *(const f4*)&sV[h8 + 4];
        f4 w0[2], w1[2];
#pragma unroll
        for (int e = 0; e < 2; ++e) {
            w0[e] = *(const f4*)&sW[tx + (e << 5)][h8];
            w1[e] = *(const f4*)&sW[tx + (e << 5)][h8 + 4];
        }
#pragma unroll
        for (int d = 0; d < 4; ++d) {
            const f4 u0 = *(const f4*)&sU[ty + (d << 4)][h8];
            const f4 u1 = *(const f4*)&sU[ty + (d << 4)][h8 + 4];
#pragma unroll
            for (int e = 0; e < 2; ++e) {
                // leaves: A'_t = 2^-8 * (1 + u_t w_t)   (u pre-scaled by 2^-8)
                const float A0 = fmaf(u0.x, w0[e].x, S8);
                const float A1 = fmaf(u0.y, w0[e].y, S8);
                const float A2 = fmaf(u0.z, w0[e].z, S8);
                const float A3 = fmaf(u0.w, w0[e].w, S8);
                const float A4 = fmaf(u1.x, w1[e].x, S8);
                const float A5 = fmaf(u1.y, w1[e].y, S8);
                const float A6 = fmaf(u1.z, w1[e].z, S8);
                const float A7 = fmaf(u1.w, w1[e].w, S8);
                // pair level
                const float m01 = A0 * A1, m23 = A2 * A3;
                const float m45 = A4 * A5, m67 = A6 * A7;
                const float t01 = fmaf(vv0.x, A1, vv0.y * A0);
                const float t23 = fmaf(vv0.z, A3, vv0.w * A2);
                const float t45 = fmaf(vv1.x, A5, vv1.y * A4);
                const float t67 = fmaf(vv1.z, A7, vv1.w * A6);
                // quad level
                const float m03 = m01 * m23, m47 = m45 * m67;
                const float t03 = fmaf(t01, m23, t23 * m01);
                const float t47 = fmaf(t45, m67, t67 * m45);
                // oct level
                const float M = m03 * m47;
                const float N = fmaf(t03, m47, t47 * m03);
                acc[d][e] = fmaf(N, __builtin_amdgcn_rcpf(M), acc[d][e]);
            }
        }
    }

    // group sum carries a 2^8 scale: true contribution = acc * 2^-8
    float* ep = Ep + (size_t)((b << 9) + i0) * 512 + j0;
#pragma unroll
    for (int d = 0; d < 4; ++d)
#pragma unroll
        for (int e = 0; e < 2; ++e)
            atomicAdd(&ep[(size_t)(ty + (d << 4)) * 512 + tx + (e << 5)],
                      acc[d][e] * S8);
}

// out[b,i,j] = Sv - Ep[b,i,j] - Ep[b,j,i]
__global__ __launch_bounds__(256) void sym_kernel(const float* __restrict__ Ep,
                                                  const float* __restrict__ v,
                                                  float* __restrict__ out) {
    __shared__ float t1[64][65];
    __shared__ float t2[64][65];
    __shared__ float red[4];

    const int tid = threadIdx.x;
    const int lane = tid & 63, wv = tid >> 6;

    float x = v[tid];
#pragma unroll
    for (int o = 32; o > 0; o >>= 1) x += __shfl_xor(x, o, 64);
    if (lane == 0) red[wv] = x;

    const int bb = blockIdx.x;
    const int b = bb >> 6;
    const int i0 = ((bb >> 3) & 7) << 6;
    const int j0 = (bb & 7) << 6;

    for (int idx = tid; idx < 4096; idx += 256) {
        const int r = idx >> 6, c = idx & 63;
        t1[r][c] = Ep[(size_t)((b << 9) + i0 + r) * 512 + j0 + c];
        t2[r][c] = Ep[(size_t)((b << 9) + j0 + r) * 512 + i0 + c];
    }
    __syncthreads();
    const float Sv = red[0] + red[1] + red[2] + red[3];
    for (int idx = tid; idx < 4096; idx += 256) {
        const int r = idx >> 6, c = idx & 63;
        out[(size_t)((b << 9) + i0 + r) * 512 + j0 + c] = Sv - (t1[r][c] + t2[c][r]);
    }
}

extern "C" void kernel_launch(void* const* d_in, const int* in_sizes, int n_in,
                              void* d_out, int out_size, void* d_ws, size_t ws_size,
                              hipStream_t stream) {
    const float* X  = (const float*)d_in[0];
    // d_in[1] = Y (unused)
    const float* W1 = (const float*)d_in[2];
    const float* b1 = (const float*)d_in[3];
    const float* W2 = (const float*)d_in[4];
    const float* b2 = (const float*)d_in[5];
    const float* Wq = (const float*)d_in[6];
    const float* bq = (const float*)d_in[7];
    const float* Wk = (const float*)d_in[8];
    const float* bk = (const float*)d_in[9];
    const float* v  = (const float*)d_in[10];
    // d_in[11] = k (unused)

    float* ws  = (float*)d_ws;
    float* h1  = ws;                 // 2048*256 = 524288 f
    float* uwb = ws + 524288;        // 2048*512 = 1048576 f
    float* Wc  = ws + 1572864;       // 512*256  = 131072 f
    float* bc  = ws + 1703936;       // 512 f
    float* Ep  = ws + 1704448;       // 1048576 f (single slice, atomically acc)
    float* out = (float*)d_out;

    // zero Ep (pairwise accumulates atomically across 4 h-chunks)
    hipMemsetAsync(Ep, 0, 1048576 * sizeof(float), stream);

    // fused: h1 = tanh(X@W1^T+b1)  and  Wc = [Wq;Wk]@W2, bc = [..]@b2 + bias
    gemm_stage1<<<160, 256, 0, stream>>>(X, W1, b1, Wq, Wk, W2, b2, bq, bk,
                                         h1, Wc, bc);
    // uwb[:, :256] = min(exp2(C2*Q - 8), 4), uwb[:, 256:] = min(exp2(C2*K), 1024)
    gemm_fullk<2><<<dim3(32, 8), 256, 0, stream>>>(h1, Wc, Wc + 65536, bc,
                                                   bc + 256, uwb, 512);
    // Ep[b,i,j] += sum_{h in chunk} v_h/(1+u w)
    pairwise_kernel<<<1024, 512, 0, stream>>>(uwb, v, Ep);
    // out = Sv - Ep - Ep^T
    sym_kernel<<<256, 256, 0, stream>>>(Ep, v, out);
}

// Round 10
// 57.437 us; speedup vs baseline: 1.1887x; 1.0904x over previous
//
#include <hip/hip_runtime.h>

// Problem: B=4, N=512, D=256, H=256, M = B*N = 2048
// out[b,i,j] = 0.5*(E + E^T),  E[b,i,j] = sum_h v[h]*tanh(Q[b,i,h]+K[b,j,h])
// tanh(q+k) = 1 - 2/(1+e^{2q}e^{2k}); u=exp2(C2*q), w=exp2(C2*k), C2=2*log2(e)
// P_ij = sum_h v_h/(1+u_ih w_jh);  out_ij = Sv - (P_ij + P_ji)
// 8-way rcp batching (1 rcp per 8 terms) via common-denominator tree.
// Overflow: u pre-scaled by 2^-8 in gemm epilogue (u' = exp2(C2*Q-8), clamp 4;
//   w = exp2(C2*K), clamp 1024).  Leaf A' = fma(u',w,2^-8) = 2^-8*(1+uw).
//   M' = prod8 <= 4096^8 ~ 8e28 (safe); fold 2^-8 into the final store.
// GEMM fold: Q = h1 @ (Wq@W2)^T + (Wq@b2+bq)
// NOTE: hipMemsetAsync(4MB) showed as a ~40us/105GB/s fill dispatch in rocprof
// (round 9) -- replaced by Ep-zeroing blocks appended to gemm_stage1's grid.

typedef float f2 __attribute__((ext_vector_type(2)));
typedef float f4 __attribute__((ext_vector_type(4)));
typedef float f32x4 __attribute__((ext_vector_type(4)));
typedef __bf16 bf16x8 __attribute__((ext_vector_type(8)));

#define C2F 2.8853900817779268f
#define S8  0.00390625f   // 2^-8

__device__ inline unsigned short f2bf(float f) {
    unsigned u = __float_as_uint(f);
    unsigned r = (u + 0x7fffu + ((u >> 16) & 1u)) >> 16;
    return (unsigned short)r;
}
__device__ inline float bf2f(unsigned short h) {
    return __uint_as_float(((unsigned)h) << 16);
}

__device__ inline void split4(const f4 a, unsigned short* hp, unsigned short* lp) {
    unsigned short h[4], l[4];
#pragma unroll
    for (int t = 0; t < 4; ++t) {
        h[t] = f2bf(a[t]);
        l[t] = f2bf(a[t] - bf2f(h[t]));
    }
    uint2 hv, lv;
    hv.x = (unsigned)h[0] | ((unsigned)h[1] << 16);
    hv.y = (unsigned)h[2] | ((unsigned)h[3] << 16);
    lv.x = (unsigned)l[0] | ((unsigned)l[1] << 16);
    lv.y = (unsigned)l[2] | ((unsigned)l[3] << 16);
    *(uint2*)hp = hv;
    *(uint2*)lp = lv;
}

// ---------------------------------------------------------------------------
// gemm_fullk: C[m,n] = act( sum_k A[m,k]*Wsel[n,k] + bias[n] ), K=256 resident.
// ACT: 1=tanh, 2: col<256 -> min(exp2(C2*x-8),4); col>=256 -> min(exp2(C2*x),1024)
// ---------------------------------------------------------------------------
template <int ACT>
__global__ __launch_bounds__(256) void gemm_fullk(
    const float* __restrict__ A, const float* __restrict__ Wa,
    const float* __restrict__ Wb, const float* __restrict__ ba,
    const float* __restrict__ bb2, float* __restrict__ C, int Nn) {
    __shared__ unsigned short sAhi[64][264];
    __shared__ unsigned short sAlo[64][264];
    __shared__ unsigned short sBhi[64][264];
    __shared__ unsigned short sBlo[64][264];

    const int tid = threadIdx.x;
    const int m0 = blockIdx.x << 6;
    const int n0 = blockIdx.y << 6;

    const float* Atile = A + (size_t)m0 * 256;
    const float* Wtile = (n0 < 256) ? (Wa + (size_t)n0 * 256)
                                    : (Wb + (size_t)(n0 - 256) * 256);
    const int col4 = (tid & 63) << 2;
    const int rgrp = tid >> 6;
#pragma unroll
    for (int t = 0; t < 16; ++t) {
        const int row = (t << 2) + rgrp;
        f4 av = *(const f4*)&Atile[(size_t)row * 256 + col4];
        f4 wv = *(const f4*)&Wtile[(size_t)row * 256 + col4];
        split4(av, &sAhi[row][col4], &sAlo[row][col4]);
        split4(wv, &sBhi[row][col4], &sBlo[row][col4]);
    }
    __syncthreads();

    const int lane = tid & 63;
    const int wav = tid >> 6;
    const int wm = wav >> 1, wn = wav & 1;
    const int fr = lane & 15;
    const int fks = (lane >> 4) << 3;

    f32x4 acc[2][2];
#pragma unroll
    for (int i = 0; i < 2; ++i)
#pragma unroll
        for (int j = 0; j < 2; ++j) acc[i][j] = (f32x4){0.f, 0.f, 0.f, 0.f};

#pragma unroll
    for (int kt = 0; kt < 256; kt += 32) {
        bf16x8 ah[2], al[2], bh[2], bl[2];
#pragma unroll
        for (int s = 0; s < 2; ++s) {
            ah[s] = *(const bf16x8*)&sAhi[(wm << 5) + (s << 4) + fr][kt + fks];
            al[s] = *(const bf16x8*)&sAlo[(wm << 5) + (s << 4) + fr][kt + fks];
            bh[s] = *(const bf16x8*)&sBhi[(wn << 5) + (s << 4) + fr][kt + fks];
            bl[s] = *(const bf16x8*)&sBlo[(wn << 5) + (s << 4) + fr][kt + fks];
        }
#pragma unroll
        for (int i = 0; i < 2; ++i)
#pragma unroll
            for (int j = 0; j < 2; ++j) {
                acc[i][j] = __builtin_amdgcn_mfma_f32_16x16x32_bf16(ah[i], bh[j], acc[i][j], 0, 0, 0);
                acc[i][j] = __builtin_amdgcn_mfma_f32_16x16x32_bf16(ah[i], bl[j], acc[i][j], 0, 0, 0);
                acc[i][j] = __builtin_amdgcn_mfma_f32_16x16x32_bf16(al[i], bh[j], acc[i][j], 0, 0, 0);
            }
    }

    const int rbase = (lane >> 4) << 2;
#pragma unroll
    for (int i = 0; i < 2; ++i) {
#pragma unroll
        for (int j = 0; j < 2; ++j) {
            const int gcol = n0 + (wn << 5) + (j << 4) + fr;
            const float bias = (ACT == 2 && gcol >= 256) ? bb2[gcol - 256] : ba[gcol];
#pragma unroll
            for (int q = 0; q < 4; ++q) {
                const int grow = m0 + (wm << 5) + (i << 4) + rbase + q;
                float x = acc[i][j][q] + bias;
                if (ACT == 1)
                    x = 1.0f - 2.0f * __builtin_amdgcn_rcpf(
                                          1.0f + __builtin_amdgcn_exp2f(C2F * x));
                if (ACT == 2) {
                    if (gcol < 256)
                        x = fminf(__builtin_amdgcn_exp2f(C2F * x - 8.0f), 4.0f);
                    else
                        x = fminf(__builtin_amdgcn_exp2f(C2F * x), 1024.0f);
                }
                C[(size_t)grow * Nn + gcol] = x;
            }
        }
    }
}

// ---------------------------------------------------------------------------
// gemm_stage1: fused launch.
//  blocks [0,128): h1 = tanh(X @ W1^T + b1)
//  blocks [128,160): Wc = [Wq;Wk] @ W2 (B not transp.), bc = Asel@b2 + bias
//  blocks [160,224): zero Ep (1M floats; replaces 40us hipMemsetAsync fill)
// ---------------------------------------------------------------------------
__global__ __launch_bounds__(256) void gemm_stage1(
    const float* __restrict__ X, const float* __restrict__ W1,
    const float* __restrict__ b1, const float* __restrict__ Wq,
    const float* __restrict__ Wk, const float* __restrict__ W2,
    const float* __restrict__ b2, const float* __restrict__ bq,
    const float* __restrict__ bk, float* __restrict__ h1,
    float* __restrict__ Wc, float* __restrict__ bc,
    float* __restrict__ Ep) {
    __shared__ unsigned short sAhi[64][264];
    __shared__ unsigned short sAlo[64][264];
    __shared__ unsigned short sBhi[64][264];
    __shared__ unsigned short sBlo[64][264];
    __shared__ float sred[64][4];

    const int tid = threadIdx.x;

    if (blockIdx.x >= 160) {
        // Ep zeroing: 64 blocks x 256 thr x 16 f4 = 1048576 floats
        const int zb = blockIdx.x - 160;
        f4* dst = (f4*)(Ep + (size_t)zb * 16384) + tid;
        const f4 z = (f4){0.f, 0.f, 0.f, 0.f};
#pragma unroll
        for (int t = 0; t < 16; ++t) dst[t * 256] = z;
        return;
    }

    const bool is_nt = (blockIdx.x >= 128);
    const int blk = is_nt ? (blockIdx.x - 128) : blockIdx.x;
    const int m0 = (blk >> 2) << 6;
    const int n0 = (blk & 3) << 6;

    const int col4 = (tid & 63) << 2;
    const int rgrp = tid >> 6;

    if (!is_nt) {
        const float* Atile = X + (size_t)m0 * 256;
        const float* Wtile = W1 + (size_t)n0 * 256;
#pragma unroll
        for (int t = 0; t < 16; ++t) {
            const int row = (t << 2) + rgrp;
            f4 av = *(const f4*)&Atile[(size_t)row * 256 + col4];
            f4 wv = *(const f4*)&Wtile[(size_t)row * 256 + col4];
            split4(av, &sAhi[row][col4], &sAlo[row][col4]);
            split4(wv, &sBhi[row][col4], &sBlo[row][col4]);
        }
    } else {
        const float* Atile = (m0 < 256) ? (Wq + (size_t)m0 * 256)
                                        : (Wk + (size_t)(m0 - 256) * 256);
#pragma unroll
        for (int t = 0; t < 16; ++t) {
            const int row = (t << 2) + rgrp;
            f4 av = *(const f4*)&Atile[(size_t)row * 256 + col4];
            split4(av, &sAhi[row][col4], &sAlo[row][col4]);
        }
        const int c4 = (tid & 15) << 2;
        const int kg = tid >> 4;
#pragma unroll
        for (int t = 0; t < 16; ++t) {
            const int k = (t << 4) + kg;
            f4 wv = *(const f4*)&W2[(size_t)k * 256 + n0 + c4];
#pragma unroll
            for (int q = 0; q < 4; ++q) {
                unsigned short hi = f2bf(wv[q]);
                sBhi[c4 + q][k] = hi;
                sBlo[c4 + q][k] = f2bf(wv[q] - bf2f(hi));
            }
        }
    }
    __syncthreads();

    const int lane = tid & 63;
    const int wav = tid >> 6;
    const int wm = wav >> 1, wn = wav & 1;
    const int fr = lane & 15;
    const int fks = (lane >> 4) << 3;

    f32x4 acc[2][2];
#pragma unroll
    for (int i = 0; i < 2; ++i)
#pragma unroll
        for (int j = 0; j < 2; ++j) acc[i][j] = (f32x4){0.f, 0.f, 0.f, 0.f};

#pragma unroll
    for (int kt = 0; kt < 256; kt += 32) {
        bf16x8 ah[2], al[2], bh[2], bl[2];
#pragma unroll
        for (int s = 0; s < 2; ++s) {
            ah[s] = *(const bf16x8*)&sAhi[(wm << 5) + (s << 4) + fr][kt + fks];
            al[s] = *(const bf16x8*)&sAlo[(wm << 5) + (s << 4) + fr][kt + fks];
            bh[s] = *(const bf16x8*)&sBhi[(wn << 5) + (s << 4) + fr][kt + fks];
            bl[s] = *(const bf16x8*)&sBlo[(wn << 5) + (s << 4) + fr][kt + fks];
        }
#pragma unroll
        for (int i = 0; i < 2; ++i)
#pragma unroll
            for (int j = 0; j < 2; ++j) {
                acc[i][j] = __builtin_amdgcn_mfma_f32_16x16x32_bf16(ah[i], bh[j], acc[i][j], 0, 0, 0);
                acc[i][j] = __builtin_amdgcn_mfma_f32_16x16x32_bf16(ah[i], bl[j], acc[i][j], 0, 0, 0);
                acc[i][j] = __builtin_amdgcn_mfma_f32_16x16x32_bf16(al[i], bh[j], acc[i][j], 0, 0, 0);
            }
    }

    const int rbase = (lane >> 4) << 2;
    if (!is_nt) {
#pragma unroll
        for (int i = 0; i < 2; ++i)
#pragma unroll
            for (int j = 0; j < 2; ++j) {
                const int gcol = n0 + (wn << 5) + (j << 4) + fr;
                const float bias = b1[gcol];
#pragma unroll
                for (int q = 0; q < 4; ++q) {
                    const int grow = m0 + (wm << 5) + (i << 4) + rbase + q;
                    float x = acc[i][j][q] + bias;
                    x = 1.0f - 2.0f * __builtin_amdgcn_rcpf(
                                          1.0f + __builtin_amdgcn_exp2f(C2F * x));
                    h1[(size_t)grow * 256 + gcol] = x;
                }
            }
    } else {
#pragma unroll
        for (int i = 0; i < 2; ++i)
#pragma unroll
            for (int j = 0; j < 2; ++j) {
                const int gcol = n0 + (wn << 5) + (j << 4) + fr;
#pragma unroll
                for (int q = 0; q < 4; ++q) {
                    const int grow = m0 + (wm << 5) + (i << 4) + rbase + q;
                    Wc[(size_t)grow * 256 + gcol] = acc[i][j][q];
                }
            }
        if ((blk & 3) == 0) {
            const int rr = tid >> 2;
            const int part = (tid & 3) << 6;
            const int grow = m0 + rr;
            const float* Ar = (grow < 256) ? &Wq[(size_t)grow * 256]
                                           : &Wk[(size_t)(grow - 256) * 256];
            float s = 0.f;
#pragma unroll
            for (int e = 0; e < 64; e += 4) {
                f4 a = *(const f4*)&Ar[part + e];
                f4 bv = *(const f4*)&b2[part + e];
                s += a[0] * bv[0] + a[1] * bv[1] + a[2] * bv[2] + a[3] * bv[3];
            }
            sred[rr][tid & 3] = s;
            __syncthreads();
            if (tid < 64) {
                float bias = sred[tid][0] + sred[tid][1] + sred[tid][2] + sred[tid][3];
                const int g2 = m0 + tid;
                bias += (g2 < 256) ? bq[g2] : bk[g2 - 256];
                bc[g2] = bias;
            }
        }
    }
}

// ---------------------------------------------------------------------------
// pairwise: per (b, i-tile, j-tile, 64-h chunk) block accumulates into Ep:
//   Ep[b,i,j] += sum_{h in chunk} v_h/(1+u_ih w_jh)       (atomicAdd, 4 chunks)
// 512 thr, 64x64 tile, 4x2 outputs/thread, 8-way rcp batching.
// ---------------------------------------------------------------------------
__global__ __launch_bounds__(512, 4) void pairwise_kernel(
    const float* __restrict__ uwb, const float* __restrict__ v,
    float* __restrict__ Ep) {
    __shared__ float sU[64][68];
    __shared__ float sW[64][68];
    __shared__ float sV[64];

    const int tid = threadIdx.x;
    const int bb = blockIdx.x;       // 1024 = (4b * 64 tiles) * 4 h-chunks
    const int hcs = bb & 3;
    const int hc = hcs << 6;
    const int tt = bb >> 2;
    const int b = tt >> 6;
    const int i0 = ((tt >> 3) & 7) << 6;
    const int j0 = (tt & 7) << 6;

    const float* ubase = uwb + (size_t)((b << 9) + i0) * 512 + hc;
    const float* wbase = uwb + (size_t)((b << 9) + j0) * 512 + 256 + hc;

    const int sr = tid >> 3;         // 0..63
    const int sc = (tid & 7) << 3;   // 0,8,..,56
    {
        f4 a0 = *(const f4*)&ubase[(size_t)sr * 512 + sc];
        f4 a1 = *(const f4*)&ubase[(size_t)sr * 512 + sc + 4];
        f4 b0 = *(const f4*)&wbase[(size_t)sr * 512 + sc];
        f4 b1 = *(const f4*)&wbase[(size_t)sr * 512 + sc + 4];
        *(f4*)&sU[sr][sc] = a0;
        *(f4*)&sU[sr][sc + 4] = a1;
        *(f4*)&sW[sr][sc] = b0;
        *(f4*)&sW[sr][sc + 4] = b1;
    }
    if (tid < 16) *(f4*)&sV[tid << 2] = *(const f4*)&v[hc + (tid << 2)];
    __syncthreads();

    const int ty = tid >> 5;   // 0..15: rows ty+16d
    const int tx = tid & 31;   // 0..31: cols tx+32e

    float acc[4][2];
#pragma unroll
    for (int d = 0; d < 4; ++d)
#pragma unroll
        for (int e = 0; e < 2; ++e) acc[d][e] = 0.f;

#pragma unroll 2
    for (int h8 = 0; h8 < 64; h8 += 8) {
        const f4 vv0 = *(const f4*)&sV[h8];
        const f4 vv1 = *(const f4*)&sV[h8 + 4];
        f4 w0[2], w1[2];
#pragma unroll
        for (int e = 0; e < 2; ++e) {
            w0[e] = *(const f4*)&sW[tx + (e << 5)][h8];
            w1[e] = *(const f4*)&sW[tx + (e << 5)][h8 + 4];
        }
#pragma unroll
        for (int d = 0; d < 4; ++d) {
            const f4 u0 = *(const f4*)&sU[ty + (d << 4)][h8];
            const f4 u1 = *(const f4*)&sU[ty + (d << 4)][h8 + 4];
#pragma unroll
            for (int e = 0; e < 2; ++e) {
                const float A0 = fmaf(u0.x, w0[e].x, S8);
                const float A1 = fmaf(u0.y, w0[e].y, S8);
                const float A2 = fmaf(u0.z, w0[e].z, S8);
                const float A3 = fmaf(u0.w, w0[e].w, S8);
                const float A4 = fmaf(u1.x, w1[e].x, S8);
                const float A5 = fmaf(u1.y, w1[e].y, S8);
                const float A6 = fmaf(u1.z, w1[e].z, S8);
                const float A7 = fmaf(u1.w, w1[e].w, S8);
                const float m01 = A0 * A1, m23 = A2 * A3;
                const float m45 = A4 * A5, m67 = A6 * A7;
                const float t01 = fmaf(vv0.x, A1, vv0.y * A0);
                const float t23 = fmaf(vv0.z, A3, vv0.w * A2);
                const float t45 = fmaf(vv1.x, A5, vv1.y * A4);
                const float t67 = fmaf(vv1.z, A7, vv1.w * A6);
                const float m03 = m01 * m23, m47 = m45 * m67;
                const float t03 = fmaf(t01, m23, t23 * m01);
                const float t47 = fmaf(t45, m67, t67 * m45);
                const float M = m03 * m47;
                const float N = fmaf(t03, m47, t47 * m03);
                acc[d][e] = fmaf(N, __builtin_amdgcn_rcpf(M), acc[d][e]);
            }
        }
    }

    float* ep = Ep + (size_t)((b << 9) + i0) * 512 + j0;
#pragma unroll
    for (int d = 0; d < 4; ++d)
#pragma unroll
        for (int e = 0; e < 2; ++e)
            atomicAdd(&ep[(size_t)(ty + (d << 4)) * 512 + tx + (e << 5)],
                      acc[d][e] * S8);
}

// out[b,i,j] = Sv - Ep[b,i,j] - Ep[b,j,i]
__global__ __launch_bounds__(256) void sym_kernel(const float* __restrict__ Ep,
                                                  const float* __restrict__ v,
                                                  float* __restrict__ out) {
    __shared__ float t1[64][65];
    __shared__ float t2[64][65];
    __shared__ float red[4];

    const int tid = threadIdx.x;
    const int lane = tid & 63, wv = tid >> 6;

    float x = v[tid];
#pragma unroll
    for (int o = 32; o > 0; o >>= 1) x += __shfl_xor(x, o, 64);
    if (lane == 0) red[wv] = x;

    const int bb = blockIdx.x;
    const int b = bb >> 6;
    const int i0 = ((bb >> 3) & 7) << 6;
    const int j0 = (bb & 7) << 6;

    for (int idx = tid; idx < 4096; idx += 256) {
        const int r = idx >> 6, c = idx & 63;
        t1[r][c] = Ep[(size_t)((b << 9) + i0 + r) * 512 + j0 + c];
        t2[r][c] = Ep[(size_t)((b << 9) + j0 + r) * 512 + i0 + c];
    }
    __syncthreads();
    const float Sv = red[0] + red[1] + red[2] + red[3];
    for (int idx = tid; idx < 4096; idx += 256) {
        const int r = idx >> 6, c = idx & 63;
        out[(size_t)((b << 9) + i0 + r) * 512 + j0 + c] = Sv - (t1[r][c] + t2[c][r]);
    }
}

extern "C" void kernel_launch(void* const* d_in, const int* in_sizes, int n_in,
                              void* d_out, int out_size, void* d_ws, size_t ws_size,
                              hipStream_t stream) {
    const float* X  = (const float*)d_in[0];
    // d_in[1] = Y (unused)
    const float* W1 = (const float*)d_in[2];
    const float* b1 = (const float*)d_in[3];
    const float* W2 = (const float*)d_in[4];
    const float* b2 = (const float*)d_in[5];
    const float* Wq = (const float*)d_in[6];
    const float* bq = (const float*)d_in[7];
    const float* Wk = (const float*)d_in[8];
    const float* bk = (const float*)d_in[9];
    const float* v  = (const float*)d_in[10];
    // d_in[11] = k (unused)

    float* ws  = (float*)d_ws;
    float* h1  = ws;                 // 2048*256 = 524288 f
    float* uwb = ws + 524288;        // 2048*512 = 1048576 f
    float* Wc  = ws + 1572864;       // 512*256  = 131072 f
    float* bc  = ws + 1703936;       // 512 f
    float* Ep  = ws + 1704448;       // 1048576 f (single slice, atomically acc)
    float* out = (float*)d_out;

    // fused: h1 = tanh(X@W1^T+b1); Wc = [Wq;Wk]@W2, bc = [..]@b2 + bias;
    // blocks [160,224) zero Ep (no hipMemsetAsync!)
    gemm_stage1<<<224, 256, 0, stream>>>(X, W1, b1, Wq, Wk, W2, b2, bq, bk,
                                         h1, Wc, bc, Ep);
    // uwb[:, :256] = min(exp2(C2*Q - 8), 4), uwb[:, 256:] = min(exp2(C2*K), 1024)
    gemm_fullk<2><<<dim3(32, 8), 256, 0, stream>>>(h1, Wc, Wc + 65536, bc,
                                                   bc + 256, uwb, 512);
    // Ep[b,i,j] += sum_{h in chunk} v_h/(1+u w)
    pairwise_kernel<<<1024, 512, 0, stream>>>(uwb, v, Ep);
    // out = Sv - Ep - Ep^T
    sym_kernel<<<256, 256, 0, stream>>>(Ep, v, out);
}